// Round 19
// baseline (235.700 us; speedup 1.0000x reference)
//
#include <hip/hip_runtime.h>
#include <stdint.h>

#define HWN 196      // tokens
#define CIN 2048     // input channels
#define DD  256      // slot dim
#define BB  64       // batch
#define NSLOT 8      // slots
#define KVPAD 224    // key pad in kbf / vT
#define MTOT 12544   // BB*HWN

typedef __attribute__((ext_vector_type(8))) short short8;
typedef __attribute__((ext_vector_type(4))) float f32x4;
typedef __attribute__((ext_vector_type(4))) unsigned short us4;

__device__ __forceinline__ ushort f2bf(float f){ union{float f;uint32_t u;}v;v.f=f;uint32_t u=v.u;return (ushort)((u+0x7FFFu+((u>>16)&1u))>>16);}
__device__ __forceinline__ float bf2f(ushort h){ union{uint32_t u;float f;}v;v.u=((uint32_t)h)<<16;return v.f;}
__device__ __forceinline__ float sigm(float x){ return 1.f/(1.f+expf(-x)); }

// Y-operand fragment from swizzled LDS [16][LD] (rows = out-col dim, K-contig)
__device__ __forceinline__ short8 ldsY(const ushort* buf, int LD, int kt, int lane){
    int row = lane & 15;
    int ch = kt*4 + (lane>>4);
    return *(const short8*)&buf[row*LD + ((ch ^ (row&7))<<3)];
}
// X-operand fragment from global [*][K] (rows = out-row dim, K-contig)
__device__ __forceinline__ short8 gX(const ushort* base, int K, int nrow, int kt, int lane){
    return *(const short8*)&base[(size_t)nrow*K + kt*32 + (lane>>4)*8];
}

// ======================= weight transposes (one kernel) =======================
struct TD { const float* s; ushort* d; int R, C, t0; };
struct TD8 { TD a[8]; };

__global__ __launch_bounds__(256) void k_prep(TD8 td){
    __shared__ float tile[32][33];
    int bt = blockIdx.x;
    int mi = 0;
    #pragma unroll
    for (int i = 1; i < 8; ++i) if (bt >= td.a[i].t0) mi = i;
    TD d = td.a[mi];
    int lt = bt - d.t0;
    int tilesx = (d.C + 31) >> 5;
    int cb = (lt % tilesx) * 32, rb = (lt / tilesx) * 32;
    int tx = threadIdx.x & 31, ty = threadIdx.x >> 5;
    for (int i = ty; i < 32; i += 8) {
        int r = rb + i, c = cb + tx;
        tile[i][tx] = (r < d.R && c < d.C) ? d.s[(size_t)r * d.C + c] : 0.f;
    }
    __syncthreads();
    for (int i = ty; i < 32; i += 8) {
        int c = cb + i, r = rb + tx;
        if (c < d.C && r < d.R) d.d[(size_t)c * d.R + r] = f2bf(tile[tx][i]);
    }
}

// ===== projection GEMM: BN=64, grid 784, XCD-quad swizzle =====
// 4 column-blocks of an A-tile land on the SAME XCD (ids differ by 8):
// A read once from HBM, 3x from that XCD's L2. More blocks -> higher occupancy.
__global__ __launch_bounds__(256) void k_proj(const float* __restrict__ x,
        const ushort* __restrict__ bT, const float* __restrict__ cb,
        const float* __restrict__ pos, ushort* __restrict__ xt){
    __shared__ ushort As[64 * 64];
    __shared__ ushort Bs[64 * 64];
    const int t = threadIdx.x;
    const int lane = t & 63;
    const int wv = t >> 6;
    const int wm = wv >> 1, wn = wv & 1;
    int mtile, nh;
    {
        int bid = blockIdx.x;
        if (bid < 768){
            int c = bid & 7, nhb = (bid >> 3) & 3, g = bid >> 5;
            mtile = g*8 + c; nh = nhb;
        } else {
            int lin = bid - 768;
            mtile = 192 + (lin >> 2); nh = lin & 3;
        }
    }
    const int bm = mtile * 64;
    const int bn = nh * 64;

    const int am = t & 63;
    const int mg = bm + am;
    const int ab = mg / HWN, ap = mg % HWN;
    const float* aptr = x + (size_t)ab * (CIN * HWN) + ap;
    const int achb = t >> 6;           // 0..3

    const int bnl = t >> 2;            // 0..63
    const int bch0 = (t & 3) * 2;
    const ushort* bptr = bT + (size_t)(bn + bnl) * CIN;

    f32x4 acc[2][2] = {};

    for (int k0 = 0; k0 < CIN; k0 += 64) {
        if (k0) __syncthreads();
        #pragma unroll
        for (int p = 0; p < 2; ++p) {
            int ch = achb + 4 * p;
            short8 av;
            #pragma unroll
            for (int j = 0; j < 8; ++j)
                av[j] = (short)f2bf(aptr[(size_t)(k0 + ch * 8 + j) * HWN]);
            *(short8*)&As[am * 64 + ((ch ^ (am & 7)) << 3)] = av;
        }
        #pragma unroll
        for (int c = 0; c < 2; ++c) {
            int ch = bch0 + c;
            short8 bv = *(const short8*)&bptr[k0 + ch * 8];
            *(short8*)&Bs[bnl * 64 + ((ch ^ (bnl & 7)) << 3)] = bv;
        }
        __syncthreads();
        #pragma unroll
        for (int kk = 0; kk < 2; ++kk) {
            short8 afr[2], bfr[2];
            #pragma unroll
            for (int mi = 0; mi < 2; ++mi) {
                int row = wm * 32 + mi * 16 + (lane & 15);
                int ch = kk * 4 + (lane >> 4);
                afr[mi] = *(const short8*)&As[row * 64 + ((ch ^ (row & 7)) << 3)];
            }
            #pragma unroll
            for (int ni = 0; ni < 2; ++ni) {
                int row = wn * 32 + ni * 16 + (lane & 15);
                int ch = kk * 4 + (lane >> 4);
                bfr[ni] = *(const short8*)&Bs[row * 64 + ((ch ^ (row & 7)) << 3)];
            }
            #pragma unroll
            for (int mi = 0; mi < 2; ++mi)
                #pragma unroll
                for (int ni = 0; ni < 2; ++ni)
                    acc[mi][ni] = __builtin_amdgcn_mfma_f32_16x16x32_bf16(
                        afr[mi], bfr[ni], acc[mi][ni], 0, 0, 0);
        }
    }
    #pragma unroll
    for (int mi = 0; mi < 2; ++mi) {
        #pragma unroll
        for (int ni = 0; ni < 2; ++ni) {
            int n = bn + wn * 32 + ni * 16 + (lane & 15);
            float cbn = cb[n];
            #pragma unroll
            for (int r = 0; r < 4; ++r) {
                int row = wm * 32 + mi * 16 + (lane >> 4) * 4 + r;
                int m = bm + row;
                int p = m % HWN;
                xt[(size_t)m * DD + n] = f2bf(acc[mi][ni][r] + cbn + pos[(size_t)p * DD + n]);
            }
        }
    }
}

// ===== fused: [blocks 0..447] LN + k/v GEMM ; [blocks 448..479] slot init + q =====
__global__ __launch_bounds__(512) void k_kvinit(const ushort* __restrict__ xt,
        const ushort* __restrict__ kwT, const ushort* __restrict__ vwT,
        const float* __restrict__ kb, const float* __restrict__ vb,
        const float* __restrict__ lng, const float* __restrict__ lnb,
        ushort* __restrict__ kbf, ushort* __restrict__ vT,
        const float* __restrict__ noise, const float* __restrict__ mu,
        const float* __restrict__ lsig,
        const ushort* __restrict__ qwT, const float* __restrict__ qb,
        const float* __restrict__ gs, const float* __restrict__ bs,
        float* __restrict__ slots, ushort* __restrict__ qbuf){
    __shared__ ushort As[32*256];
    __shared__ float Sld[16*256];
    __shared__ float part[8][16][2];
    __shared__ float stats[16][2];
    const int t = threadIdx.x, lane = t & 63, wv = t >> 6;
    if (blockIdx.x < 448){
        const int b = blockIdx.x / 7, pblk = blockIdx.x % 7;
        {   // stage 32 rows with LayerNorm fused. 16 threads per row.
            int row = t >> 4, seg = t & 15;
            int grow = b*HWN + pblk*32 + row;
            if (grow > MTOT-1) grow = MTOT-1;
            const ushort* src = &xt[(size_t)grow*DD + seg*16];
            short8 v0 = *(const short8*)&src[0];
            short8 v1 = *(const short8*)&src[8];
            float f[16];
            #pragma unroll
            for (int j = 0; j < 8; ++j){ f[j] = bf2f((ushort)v0[j]); f[8+j] = bf2f((ushort)v1[j]); }
            float s = 0.f, sq = 0.f;
            #pragma unroll
            for (int j = 0; j < 16; ++j){ s += f[j]; sq += f[j]*f[j]; }
            #pragma unroll
            for (int m = 8; m >= 1; m >>= 1){ s += __shfl_xor(s, m, 64); sq += __shfl_xor(sq, m, 64); }
            float mean = s * (1.f/256.f);
            float rs = rsqrtf(sq*(1.f/256.f) - mean*mean + 1e-5f);
            int d0 = seg*16;
            short8 o0, o1;
            #pragma unroll
            for (int j = 0; j < 8; ++j){
                o0[j] = (short)f2bf((f[j]   - mean)*rs*lng[d0+j]   + lnb[d0+j]);
                o1[j] = (short)f2bf((f[8+j] - mean)*rs*lng[d0+8+j] + lnb[d0+8+j]);
            }
            int ch0 = seg*2;
            *(short8*)&As[row*256 + ((ch0^(row&7))<<3)] = o0;
            *(short8*)&As[row*256 + (((ch0+1)^(row&7))<<3)] = o1;
        }
        __syncthreads();
        f32x4 acck[2][2] = {}, accv[2][2] = {};
        const int n0 = wv*32;
        #pragma unroll
        for (int kt = 0; kt < 8; ++kt){
            short8 afr[2];
            #pragma unroll
            for (int mi = 0; mi < 2; ++mi){
                int row = mi*16 + (lane&15);
                int ch = kt*4 + (lane>>4);
                afr[mi] = *(const short8*)&As[row*256 + ((ch^(row&7))<<3)];
            }
            #pragma unroll
            for (int ni = 0; ni < 2; ++ni){
                int n = n0 + ni*16 + (lane&15);
                int koff = kt*32 + (lane>>4)*8;
                short8 bk = *(const short8*)&kwT[(size_t)n*DD + koff];
                short8 bv = *(const short8*)&vwT[(size_t)n*DD + koff];
                #pragma unroll
                for (int mi = 0; mi < 2; ++mi){
                    acck[mi][ni] = __builtin_amdgcn_mfma_f32_16x16x32_bf16(afr[mi], bk, acck[mi][ni],0,0,0);
                    accv[mi][ni] = __builtin_amdgcn_mfma_f32_16x16x32_bf16(afr[mi], bv, accv[mi][ni],0,0,0);
                }
            }
        }
        #pragma unroll
        for (int mi = 0; mi < 2; ++mi){
            #pragma unroll
            for (int ni = 0; ni < 2; ++ni){
                int n = n0 + ni*16 + (lane&15);
                float kbn = kb[n], vbn = vb[n];
                int pl0 = pblk*32 + mi*16 + (lane>>4)*4;
                us4 pk;
                #pragma unroll
                for (int r = 0; r < 4; ++r){
                    kbf[((size_t)b*KVPAD + pl0 + r)*DD + n] = f2bf(acck[mi][ni][r] + kbn);
                    pk[r] = f2bf(accv[mi][ni][r] + vbn);
                }
                *(us4*)&vT[((size_t)b*DD + n)*KVPAD + pl0] = pk;
            }
        }
    } else {
        // ===== slot init: slots0 + LN_s + q (reuses As as Ysn) =====
        ushort* Ysn = As;
        const int bb = blockIdx.x - 448, rbase = bb*16;
        const int w = wv;
        {
            int row = t>>5, ch = t&31; int d = ch*8;
            f32x4 n0 = *(const f32x4*)&noise[(size_t)(rbase+row)*DD + d];
            f32x4 n1 = *(const f32x4*)&noise[(size_t)(rbase+row)*DD + d + 4];
            f32x4 m0 = *(const f32x4*)&mu[d];
            f32x4 m1 = *(const f32x4*)&mu[d+4];
            f32x4 l0 = *(const f32x4*)&lsig[d];
            f32x4 l1 = *(const f32x4*)&lsig[d+4];
            f32x4 s0, s1;
            #pragma unroll
            for (int j = 0; j < 4; ++j){
                s0[j] = m0[j] + expf(l0[j])*n0[j];
                s1[j] = m1[j] + expf(l1[j])*n1[j];
            }
            *(f32x4*)&slots[(size_t)(rbase+row)*DD + d] = s0;
            *(f32x4*)&slots[(size_t)(rbase+row)*DD + d + 4] = s1;
            *(f32x4*)&Sld[row*256 + d] = s0;
            *(f32x4*)&Sld[row*256 + d + 4] = s1;
        }
        __syncthreads();
        f32x4 sv[2];
        #pragma unroll
        for (int sub = 0; sub < 2; ++sub){
            int d0 = w*32 + sub*16 + (lane>>4)*4;
            sv[sub] = *(const f32x4*)&Sld[(lane&15)*256 + d0];
        }
        {
            float lsum = 0.f, lsq = 0.f;
            #pragma unroll
            for (int sub = 0; sub < 2; ++sub)
                #pragma unroll
                for (int r = 0; r < 4; ++r){ float v = sv[sub][r]; lsum += v; lsq += v*v; }
            lsum += __shfl_xor(lsum, 16, 64); lsum += __shfl_xor(lsum, 32, 64);
            lsq  += __shfl_xor(lsq, 16, 64);  lsq  += __shfl_xor(lsq, 32, 64);
            if (lane < 16){ part[w][lane][0] = lsum; part[w][lane][1] = lsq; }
        }
        __syncthreads();
        if (t < 16){
            float a = 0.f, c = 0.f;
            #pragma unroll
            for (int i = 0; i < 8; ++i){ a += part[i][t][0]; c += part[i][t][1]; }
            float mean = a*(1.f/256.f);
            stats[t][0] = mean;
            stats[t][1] = rsqrtf(c*(1.f/256.f) - mean*mean + 1e-5f);
        }
        __syncthreads();
        {
            int slot = lane&15;
            float mean = stats[slot][0], rs = stats[slot][1];
            #pragma unroll
            for (int sub = 0; sub < 2; ++sub){
                int d0 = w*32 + sub*16 + (lane>>4)*4;
                f32x4 g4 = *(const f32x4*)&gs[d0];
                f32x4 b4 = *(const f32x4*)&bs[d0];
                us4 o;
                #pragma unroll
                for (int r = 0; r < 4; ++r) o[r] = f2bf((sv[sub][r]-mean)*rs*g4[r] + b4[r]);
                int ch = d0>>3;
                *(us4*)&Ysn[slot*256 + ((ch^(slot&7))<<3) + (d0&7)] = o;
            }
        }
        __syncthreads();
        f32x4 qa[2] = {};
        #pragma unroll
        for (int kt = 0; kt < 8; ++kt){
            short8 ysn = ldsY(Ysn, 256, kt, lane);
            #pragma unroll
            for (int sub = 0; sub < 2; ++sub){
                int nrow = w*32 + sub*16 + (lane&15);
                short8 xx = gX(qwT, 256, nrow, kt, lane);
                qa[sub] = __builtin_amdgcn_mfma_f32_16x16x32_bf16(xx, ysn, qa[sub], 0,0,0);
            }
        }
        #pragma unroll
        for (int sub = 0; sub < 2; ++sub){
            int qd0 = w*32 + sub*16 + (lane>>4)*4;
            f32x4 qb4 = *(const f32x4*)&qb[qd0];
            us4 o;
            #pragma unroll
            for (int r = 0; r < 4; ++r) o[r] = f2bf((qa[sub][r]+qb4[r])*0.0625f);
            *(us4*)&qbuf[(size_t)(rbase+(lane&15))*DD + qd0] = o;
        }
    }
}

// softmax-over-slots epilogue for one 16-key tile; returns partial key-sum
__device__ __forceinline__ float sm_ep(f32x4 acc, int f, int lane, ushort* Xat, int srow){
    int k0 = f*16 + (lane>>4)*4;
    us4 o;
    float ps = 0.f;
    #pragma unroll
    for (int r = 0; r < 4; ++r){
        float v = acc[r];
        float mx = v;
        mx = fmaxf(mx, __shfl_xor(mx, 1, 64));
        mx = fmaxf(mx, __shfl_xor(mx, 2, 64));
        mx = fmaxf(mx, __shfl_xor(mx, 4, 64));
        float e = expf(v - mx);
        float se = e;
        se += __shfl_xor(se, 1, 64);
        se += __shfl_xor(se, 2, 64);
        se += __shfl_xor(se, 4, 64);
        float val = e/se + 1e-8f;
        if (k0 + r >= HWN) val = 0.f;
        ps += val;
        o[r] = f2bf(val);
    }
    int ch = k0 >> 3;
    *(us4*)&Xat[srow*256 + ((ch^(srow&7))<<3) + (k0&7)] = o;
    return ps;
}

// ======================= merged slot iteration, 16 waves =======================
__global__ __launch_bounds__(1024, 2) void k_slot(
        const ushort* __restrict__ qbuf, const ushort* __restrict__ kbf,
        const ushort* __restrict__ vT, float* __restrict__ slots,
        ushort* __restrict__ qout,
        const ushort* __restrict__ wihT, const ushort* __restrict__ whhT,
        const float* __restrict__ bih, const float* __restrict__ bhh,
        const ushort* __restrict__ w1T, const float* __restrict__ b1,
        const ushort* __restrict__ w2T, const float* __restrict__ b2,
        const float* __restrict__ gff, const float* __restrict__ bff,
        const float* __restrict__ gs, const float* __restrict__ bs,
        const ushort* __restrict__ qwT, const float* __restrict__ qb,
        float* __restrict__ out_slots, float* __restrict__ out_attn,
        int final_){
    __shared__ ushort Yq[16*256];
    __shared__ ushort Xat[16*256];
    __shared__ ushort Yupd[16*256];
    __shared__ ushort Yslb[16*256];
    __shared__ ushort Ysn[16*256];
    __shared__ ushort Yh[16*512];
    __shared__ float wpart[16][16];
    __shared__ float part[16][16][2];
    const int t = threadIdx.x, lane = t & 63, w = t >> 6;
    const int b = blockIdx.x;
    const int rbase = b * NSLOT;
    const int srow = lane & 15;
    const int srd = (srow < NSLOT) ? srow : 0;

    if (t < 256){
        int row = t>>5, ch = t&31;
        short8 v = *(const short8*)&qbuf[(size_t)(rbase+row)*DD + ch*8];
        *(short8*)&Yq[row*256 + ((ch^(row&7))<<3)] = v;
        f32x4 s0 = *(const f32x4*)&slots[(size_t)(rbase+row)*DD + ch*8];
        f32x4 s1 = *(const f32x4*)&slots[(size_t)(rbase+row)*DD + ch*8 + 4];
        short8 sv;
        #pragma unroll
        for (int j = 0; j < 4; ++j){ sv[j] = (short)f2bf(s0[j]); sv[4+j] = (short)f2bf(s1[j]); }
        *(short8*)&Yslb[row*256 + ((ch^(row&7))<<3)] = sv;
    } else if (t < 512){
        int i = t - 256;
        int row = (i>>5) + 8, ch = i&31;
        short8 z;
        #pragma unroll
        for (int j = 0; j < 8; ++j) z[j] = 0;
        *(short8*)&Yq[row*256 + ((ch^(row&7))<<3)] = z;
        *(short8*)&Yupd[row*256 + ((ch^(row&7))<<3)] = z;
        *(short8*)&Yslb[row*256 + ((ch^(row&7))<<3)] = z;
    }
    __syncthreads();
    // ===== QK^T + softmax over slots: 1 key-tile per wave (14 of 16 active) =====
    if (w < 14){
        short8 yf[8];
        #pragma unroll
        for (int kt = 0; kt < 8; ++kt) yf[kt] = ldsY(Yq, 256, kt, lane);
        const ushort* kb_ = kbf + (size_t)b*KVPAD*DD;
        const int r0 = w*16 + (lane&15);
        short8 xa[2];
        xa[0] = gX(kb_, 256, r0, 0, lane);
        f32x4 accA = {};
        #pragma unroll
        for (int kt = 0; kt < 8; ++kt){
            int cu = kt & 1, nx = cu ^ 1;
            if (kt < 7) xa[nx] = gX(kb_, 256, r0, kt+1, lane);
            accA = __builtin_amdgcn_mfma_f32_16x16x32_bf16(xa[cu], yf[kt], accA, 0,0,0);
        }
        float ps = sm_ep(accA, w, lane, Xat, srow);
        ps += __shfl_xor(ps, 16, 64);
        ps += __shfl_xor(ps, 32, 64);
        if (lane < 16) wpart[w][lane] = ps;
    } else {
        if (lane < 16) wpart[w][lane] = 0.f;
    }
    __syncthreads();
    // ===== PV: 1 d-tile per wave; per-thread invk from wpart (no extra barrier) =====
    f32x4 pv;
    {
        short8 xat[7];
        #pragma unroll
        for (int kt = 0; kt < 7; ++kt) xat[kt] = ldsY(Xat, 256, kt, lane);
        const ushort* vb_ = vT + (size_t)b*DD*KVPAD;
        const int d0r = w*16 + (lane&15);
        short8 ya[2];
        ya[0] = gX(vb_, KVPAD, d0r, 0, lane);
        f32x4 aA = {};
        #pragma unroll
        for (int kt = 0; kt < 7; ++kt){
            int cu = kt & 1, nx = cu ^ 1;
            if (kt < 6) ya[nx] = gX(vb_, KVPAD, d0r, kt+1, lane);
            aA = __builtin_amdgcn_mfma_f32_16x16x32_bf16(xat[kt], ya[cu], aA, 0,0,0);
        }
        pv = aA;
    }
    {
        f32x4 iv;
        #pragma unroll
        for (int r = 0; r < 4; ++r){
            int s2 = (lane>>4)*4 + r;
            float s = 0.f;
            #pragma unroll
            for (int i = 0; i < 16; ++i) s += wpart[i][s2];
            iv[r] = 1.f/s;
        }
        int d0 = w*16;
        #pragma unroll
        for (int r = 0; r < 4; ++r){
            int s2 = (lane>>4)*4 + r;
            if (s2 < NSLOT){
                int d = d0 + (lane&15);
                int ch = d >> 3;
                Yupd[s2*256 + ((ch^(s2&7))<<3) + (d&7)] = f2bf(pv[r]*iv[r]);
            }
        }
    }
    if (final_){
        for (int idx = t; idx < NSLOT*HWN; idx += 1024){
            int slot = idx/HWN, key = idx - slot*HWN;
            float s = 0.f;
            #pragma unroll
            for (int i = 0; i < 16; ++i) s += wpart[i][slot];
            int ch = key >> 3;
            out_attn[(size_t)b*NSLOT*HWN + idx] =
                bf2f(Xat[slot*256 + ((ch^(slot&7))<<3) + (key&7)]) / s;
        }
    }
    __syncthreads();
    // ===== gi/gh GEMMs: 3 gate-frags per wave =====
    f32x4 gi[3] = {}, gh[3] = {};
    {
        int nrw[3];
        #pragma unroll
        for (int g = 0; g < 3; ++g) nrw[g] = g*256 + w*16 + (lane&15);
        short8 xw[2][6];
        #pragma unroll
        for (int g = 0; g < 3; ++g){
            xw[0][g]   = gX(wihT, 256, nrw[g], 0, lane);
            xw[0][3+g] = gX(whhT, 256, nrw[g], 0, lane);
        }
        #pragma unroll
        for (int kt = 0; kt < 8; ++kt){
            int cu = kt & 1, nx = cu ^ 1;
            if (kt < 7){
                #pragma unroll
                for (int g = 0; g < 3; ++g){
                    xw[nx][g]   = gX(wihT, 256, nrw[g], kt+1, lane);
                    xw[nx][3+g] = gX(whhT, 256, nrw[g], kt+1, lane);
                }
            }
            short8 yu = ldsY(Yupd, 256, kt, lane);
            short8 ys = ldsY(Yslb, 256, kt, lane);
            #pragma unroll
            for (int g = 0; g < 3; ++g){
                gi[g] = __builtin_amdgcn_mfma_f32_16x16x32_bf16(xw[cu][g],   yu, gi[g], 0,0,0);
                gh[g] = __builtin_amdgcn_mfma_f32_16x16x32_bf16(xw[cu][3+g], ys, gh[g], 0,0,0);
            }
        }
    }
    // ===== GRU combine (lane-local triplets, 16 dims per wave) =====
    f32x4 snew;
    {
        int d0 = w*16 + (lane>>4)*4;
        f32x4 sp  = *(const f32x4*)&slots[(size_t)(rbase + srd)*DD + d0];
        f32x4 bir = *(const f32x4*)&bih[d0];
        f32x4 biz = *(const f32x4*)&bih[256 + d0];
        f32x4 bin = *(const f32x4*)&bih[512 + d0];
        f32x4 bhr = *(const f32x4*)&bhh[d0];
        f32x4 bhz = *(const f32x4*)&bhh[256 + d0];
        f32x4 bhn = *(const f32x4*)&bhh[512 + d0];
        #pragma unroll
        for (int r = 0; r < 4; ++r){
            float ir = gi[0][r] + bir[r];
            float iz = gi[1][r] + biz[r];
            float in_ = gi[2][r] + bin[r];
            float hr = gh[0][r] + bhr[r];
            float hz = gh[1][r] + bhz[r];
            float hn = gh[2][r] + bhn[r];
            float rr = sigm(ir + hr);
            float zz = sigm(iz + hz);
            float nn = tanhf(in_ + rr*hn);
            snew[r] = (1.f - zz)*nn + zz*sp[r];
        }
    }
    // ===== LN_ff (single-barrier) =====
    {
        float lsum = 0.f, lsq = 0.f;
        #pragma unroll
        for (int r = 0; r < 4; ++r){ float v = snew[r]; lsum += v; lsq += v*v; }
        lsum += __shfl_xor(lsum, 16, 64); lsum += __shfl_xor(lsum, 32, 64);
        lsq  += __shfl_xor(lsq, 16, 64);  lsq  += __shfl_xor(lsq, 32, 64);
        if (lane < 16){ part[w][lane][0] = lsum; part[w][lane][1] = lsq; }
    }
    __syncthreads();
    {
        float a = 0.f, c = 0.f;
        #pragma unroll
        for (int i = 0; i < 16; ++i){ a += part[i][srow][0]; c += part[i][srow][1]; }
        float mean = a*(1.f/256.f);
        float rs = rsqrtf(c*(1.f/256.f) - mean*mean + 1e-5f);
        int d0 = w*16 + (lane>>4)*4;
        f32x4 g4 = *(const f32x4*)&gff[d0];
        f32x4 b4 = *(const f32x4*)&bff[d0];
        us4 o;
        #pragma unroll
        for (int r = 0; r < 4; ++r) o[r] = f2bf((snew[r]-mean)*rs*g4[r] + b4[r]);
        int ch = d0 >> 3;
        *(us4*)&Ysn[srow*256 + ((ch^(srow&7))<<3) + (d0&7)] = o;
    }
    __syncthreads();
    // ===== ff1: 2 frags per wave =====
    {
        int nr1[2];
        #pragma unroll
        for (int s2 = 0; s2 < 2; ++s2) nr1[s2] = w*32 + s2*16 + (lane&15);
        short8 xw1[2][2];
        #pragma unroll
        for (int s2 = 0; s2 < 2; ++s2) xw1[0][s2] = gX(w1T, 256, nr1[s2], 0, lane);
        f32x4 hh[2] = {};
        #pragma unroll
        for (int kt = 0; kt < 8; ++kt){
            int cu = kt & 1, nx = cu ^ 1;
            if (kt < 7){
                #pragma unroll
                for (int s2 = 0; s2 < 2; ++s2) xw1[nx][s2] = gX(w1T, 256, nr1[s2], kt+1, lane);
            }
            short8 ysn = ldsY(Ysn, 256, kt, lane);
            #pragma unroll
            for (int s2 = 0; s2 < 2; ++s2)
                hh[s2] = __builtin_amdgcn_mfma_f32_16x16x32_bf16(xw1[cu][s2], ysn, hh[s2], 0,0,0);
        }
        #pragma unroll
        for (int s2 = 0; s2 < 2; ++s2){
            int n0 = w*32 + s2*16 + (lane>>4)*4;
            f32x4 b14 = *(const f32x4*)&b1[n0];
            us4 o;
            #pragma unroll
            for (int r = 0; r < 4; ++r) o[r] = f2bf(fmaxf(hh[s2][r] + b14[r], 0.f));
            int ch = n0 >> 3;
            *(us4*)&Yh[srow*512 + ((ch^(srow&7))<<3) + (n0&7)] = o;
        }
    }
    __syncthreads();
    // ===== ff2 + residual: 1 frag per wave, K=512 =====
    f32x4 ns;
    {
        int nr2 = w*16 + (lane&15);
        short8 xw2[2];
        xw2[0] = gX(w2T, 512, nr2, 0, lane);
        f32x4 o2 = {};
        #pragma unroll
        for (int kt = 0; kt < 16; ++kt){
            int cu = kt & 1, nx = cu ^ 1;
            if (kt < 15) xw2[nx] = gX(w2T, 512, nr2, kt+1, lane);
            short8 yh = ldsY(Yh, 512, kt, lane);
            o2 = __builtin_amdgcn_mfma_f32_16x16x32_bf16(xw2[cu], yh, o2, 0,0,0);
        }
        float* dst = final_ ? out_slots : slots;
        int d0 = w*16 + (lane>>4)*4;
        f32x4 b24 = *(const f32x4*)&b2[d0];
        #pragma unroll
        for (int r = 0; r < 4; ++r) ns[r] = o2[r] + b24[r] + snew[r];
        if (srow < NSLOT)
            *(f32x4*)&dst[(size_t)(rbase + srow)*DD + d0] = ns;
    }
    if (final_) return;
    // ===== LN_s + next q (single-barrier LN) =====
    {
        float lsum = 0.f, lsq = 0.f;
        #pragma unroll
        for (int r = 0; r < 4; ++r){ float v = ns[r]; lsum += v; lsq += v*v; }
        lsum += __shfl_xor(lsum, 16, 64); lsum += __shfl_xor(lsum, 32, 64);
        lsq  += __shfl_xor(lsq, 16, 64);  lsq  += __shfl_xor(lsq, 32, 64);
        if (lane < 16){ part[w][lane][0] = lsum; part[w][lane][1] = lsq; }
    }
    __syncthreads();
    {
        float a = 0.f, c = 0.f;
        #pragma unroll
        for (int i = 0; i < 16; ++i){ a += part[i][srow][0]; c += part[i][srow][1]; }
        float mean = a*(1.f/256.f);
        float rs = rsqrtf(c*(1.f/256.f) - mean*mean + 1e-5f);
        int d0 = w*16 + (lane>>4)*4;
        f32x4 g4 = *(const f32x4*)&gs[d0];
        f32x4 b4 = *(const f32x4*)&bs[d0];
        us4 o;
        #pragma unroll
        for (int r = 0; r < 4; ++r) o[r] = f2bf((ns[r]-mean)*rs*g4[r] + b4[r]);
        int ch = d0 >> 3;
        *(us4*)&Ysn[srow*256 + ((ch^(srow&7))<<3) + (d0&7)] = o;
    }
    __syncthreads();
    {
        int nrq = w*16 + (lane&15);
        short8 xq[2];
        xq[0] = gX(qwT, 256, nrq, 0, lane);
        f32x4 qa = {};
        #pragma unroll
        for (int kt = 0; kt < 8; ++kt){
            int cu = kt & 1, nx = cu ^ 1;
            if (kt < 7) xq[nx] = gX(qwT, 256, nrq, kt+1, lane);
            short8 ysn = ldsY(Ysn, 256, kt, lane);
            qa = __builtin_amdgcn_mfma_f32_16x16x32_bf16(xq[cu], ysn, qa, 0,0,0);
        }
        int qd0 = w*16 + (lane>>4)*4;
        f32x4 qb4 = *(const f32x4*)&qb[qd0];
        us4 o;
        #pragma unroll
        for (int r = 0; r < 4; ++r) o[r] = f2bf((qa[r]+qb4[r])*0.0625f);
        if (srow < NSLOT)
            *(us4*)&qout[(size_t)(rbase + srow)*DD + qd0] = o;
    }
}

extern "C" void kernel_launch(void* const* d_in, const int* in_sizes, int n_in,
                              void* d_out, int out_size, void* d_ws, size_t ws_size,
                              hipStream_t stream) {
    const float* x      = (const float*)d_in[0];
    const float* noise  = (const float*)d_in[1];
    const float* conv_w = (const float*)d_in[2];
    const float* conv_b = (const float*)d_in[3];
    const float* pos    = (const float*)d_in[4];
    const float* mu     = (const float*)d_in[5];
    const float* logsig = (const float*)d_in[6];
    const float* qw  = (const float*)d_in[7];
    const float* qb  = (const float*)d_in[8];
    const float* kw  = (const float*)d_in[9];
    const float* kb  = (const float*)d_in[10];
    const float* vw  = (const float*)d_in[11];
    const float* vb  = (const float*)d_in[12];
    const float* wih = (const float*)d_in[13];
    const float* whh = (const float*)d_in[14];
    const float* bih = (const float*)d_in[15];
    const float* bhh = (const float*)d_in[16];
    const float* w1  = (const float*)d_in[17];
    const float* b1  = (const float*)d_in[18];
    const float* w2  = (const float*)d_in[19];
    const float* b2  = (const float*)d_in[20];
    const float* g_in = (const float*)d_in[21];
    const float* b_in = (const float*)d_in[22];
    const float* g_s  = (const float*)d_in[23];
    const float* b_s  = (const float*)d_in[24];
    const float* g_ff = (const float*)d_in[25];
    const float* b_ff = (const float*)d_in[26];

    char* w = (char*)d_ws;
    ushort* kbf    = (ushort*)w; w += (size_t)BB*KVPAD*DD*2;
    ushort* vT     = (ushort*)w; w += (size_t)BB*DD*KVPAD*2;
    ushort* cwT    = (ushort*)w; w += (size_t)DD*CIN*2;
    ushort* qwT    = (ushort*)w; w += (size_t)DD*DD*2;
    ushort* kwT    = (ushort*)w; w += (size_t)DD*DD*2;
    ushort* vwT    = (ushort*)w; w += (size_t)DD*DD*2;
    ushort* wihT   = (ushort*)w; w += (size_t)768*DD*2;
    ushort* whhT   = (ushort*)w; w += (size_t)768*DD*2;
    ushort* w1T    = (ushort*)w; w += (size_t)512*DD*2;
    ushort* w2T    = (ushort*)w; w += (size_t)DD*512*2;
    ushort* qbb    = (ushort*)w; w += (size_t)BB*NSLOT*DD*2;
    float*  slotsb = (float*)w;  w += (size_t)BB*NSLOT*DD*4;
    ushort* xt     = (ushort*)w; w += (size_t)MTOT*DD*2;

    float* out_slots = (float*)d_out;
    float* out_attn  = (float*)d_out + (size_t)BB*NSLOT*DD;

    TD8 td;
    td.a[0] = { conv_w, cwT, 2048, 256,    0 };
    td.a[1] = { qw,     qwT,  256, 256,  512 };
    td.a[2] = { kw,     kwT,  256, 256,  576 };
    td.a[3] = { vw,     vwT,  256, 256,  640 };
    td.a[4] = { wih,    wihT, 256, 768,  704 };
    td.a[5] = { whh,    whhT, 256, 768,  896 };
    td.a[6] = { w1,     w1T,  256, 512, 1088 };
    td.a[7] = { w2,     w2T,  512, 256, 1216 };

    k_prep<<<1344, 256, 0, stream>>>(td);
    k_proj<<<784, 256, 0, stream>>>(x, cwT, conv_b, pos, xt);
    k_kvinit<<<480, 512, 0, stream>>>(xt, kwT, vwT, kb, vb, g_in, b_in, kbf, vT,
                                      noise, mu, logsig, qwT, qb, g_s, b_s,
                                      slotsb, qbb);
    for (int it = 0; it < 3; ++it){
        k_slot<<<BB, 1024, 0, stream>>>(qbb, kbf, vT, slotsb, qbb,
                                        wihT, whhT, bih, bhh, w1T, b1, w2T, b2,
                                        g_ff, b_ff, g_s, b_s, qwT, qb,
                                        out_slots, out_attn, it == 2);
    }
}

// Round 20
// 221.519 us; speedup vs baseline: 1.0640x; 1.0640x over previous
//
#include <hip/hip_runtime.h>
#include <stdint.h>

#define HWN 196      // tokens
#define CIN 2048     // input channels
#define DD  256      // slot dim
#define BB  64       // batch
#define NSLOT 8      // slots
#define KVPAD 224    // key pad in kbf / vT
#define MTOT 12544   // BB*HWN

typedef __attribute__((ext_vector_type(8))) short short8;
typedef __attribute__((ext_vector_type(4))) float f32x4;
typedef __attribute__((ext_vector_type(4))) unsigned short us4;

__device__ __forceinline__ ushort f2bf(float f){ union{float f;uint32_t u;}v;v.f=f;uint32_t u=v.u;return (ushort)((u+0x7FFFu+((u>>16)&1u))>>16);}
__device__ __forceinline__ float bf2f(ushort h){ union{uint32_t u;float f;}v;v.u=((uint32_t)h)<<16;return v.f;}
__device__ __forceinline__ float sigm(float x){ return 1.f/(1.f+expf(-x)); }

// Y-operand fragment from swizzled LDS [16][LD] (rows = out-col dim, K-contig)
__device__ __forceinline__ short8 ldsY(const ushort* buf, int LD, int kt, int lane){
    int row = lane & 15;
    int ch = kt*4 + (lane>>4);
    return *(const short8*)&buf[row*LD + ((ch ^ (row&7))<<3)];
}
// X-operand fragment from global [*][K] (rows = out-row dim, K-contig)
__device__ __forceinline__ short8 gX(const ushort* base, int K, int nrow, int kt, int lane){
    return *(const short8*)&base[(size_t)nrow*K + kt*32 + (lane>>4)*8];
}

// ======================= weight transposes (one kernel) =======================
struct TD { const float* s; ushort* d; int R, C, t0; };
struct TD8 { TD a[8]; };

__global__ __launch_bounds__(256) void k_prep(TD8 td){
    __shared__ float tile[32][33];
    int bt = blockIdx.x;
    int mi = 0;
    #pragma unroll
    for (int i = 1; i < 8; ++i) if (bt >= td.a[i].t0) mi = i;
    TD d = td.a[mi];
    int lt = bt - d.t0;
    int tilesx = (d.C + 31) >> 5;
    int cb = (lt % tilesx) * 32, rb = (lt / tilesx) * 32;
    int tx = threadIdx.x & 31, ty = threadIdx.x >> 5;
    for (int i = ty; i < 32; i += 8) {
        int r = rb + i, c = cb + tx;
        tile[i][tx] = (r < d.R && c < d.C) ? d.s[(size_t)r * d.C + c] : 0.f;
    }
    __syncthreads();
    for (int i = ty; i < 32; i += 8) {
        int c = cb + i, r = rb + tx;
        if (c < d.C && r < d.R) d.d[(size_t)c * d.R + r] = f2bf(tile[tx][i]);
    }
}

// ===== projection GEMM (R1 structure): xt = x^T @ cwT + cb + pos, bf16 out =====
// 1-D grid 392 with XCD-pairing swizzle: both n-halves of an A-tile land on
// the SAME XCD (ids differ by 8) -> 2nd A-read hits that XCD's L2.
__global__ __launch_bounds__(256) void k_proj(const float* __restrict__ x,
        const ushort* __restrict__ bT, const float* __restrict__ cb,
        const float* __restrict__ pos, ushort* __restrict__ xt){
    __shared__ ushort As[64 * 64];
    __shared__ ushort Bs[128 * 64];
    const int t = threadIdx.x;
    const int lane = t & 63;
    const int wv = t >> 6;
    const int wm = wv >> 1, wn = wv & 1;
    int mtile, nh;
    {
        int bid = blockIdx.x;
        if (bid < 384){
            int c = bid & 7, nhb = (bid >> 3) & 1, g = bid >> 4;
            mtile = g*8 + c; nh = nhb;
        } else {
            int lin = bid - 384;
            mtile = 192 + (lin >> 1); nh = lin & 1;
        }
    }
    const int bm = mtile * 64;
    const int bn = nh * 128;

    const int am = t & 63;
    const int mg = bm + am;
    const int ab = mg / HWN, ap = mg % HWN;
    const float* aptr = x + (size_t)ab * (CIN * HWN) + ap;
    const int achb = t >> 6;           // 0..3

    const int bnl = t >> 1;            // 0..127
    const int bch0 = (t & 1) * 4;
    const ushort* bptr = bT + (size_t)(bn + bnl) * CIN;

    f32x4 acc[2][4] = {};

    for (int k0 = 0; k0 < CIN; k0 += 64) {
        if (k0) __syncthreads();
        #pragma unroll
        for (int p = 0; p < 2; ++p) {
            int ch = achb + 4 * p;
            short8 av;
            #pragma unroll
            for (int j = 0; j < 8; ++j)
                av[j] = (short)f2bf(aptr[(size_t)(k0 + ch * 8 + j) * HWN]);
            *(short8*)&As[am * 64 + ((ch ^ (am & 7)) << 3)] = av;
        }
        #pragma unroll
        for (int c = 0; c < 4; ++c) {
            int ch = bch0 + c;
            short8 bv = *(const short8*)&bptr[k0 + ch * 8];
            *(short8*)&Bs[bnl * 64 + ((ch ^ (bnl & 7)) << 3)] = bv;
        }
        __syncthreads();
        #pragma unroll
        for (int kk = 0; kk < 2; ++kk) {
            short8 afr[2], bfr[4];
            #pragma unroll
            for (int mi = 0; mi < 2; ++mi) {
                int row = wm * 32 + mi * 16 + (lane & 15);
                int ch = kk * 4 + (lane >> 4);
                afr[mi] = *(const short8*)&As[row * 64 + ((ch ^ (row & 7)) << 3)];
            }
            #pragma unroll
            for (int ni = 0; ni < 4; ++ni) {
                int row = wn * 64 + ni * 16 + (lane & 15);
                int ch = kk * 4 + (lane >> 4);
                bfr[ni] = *(const short8*)&Bs[row * 64 + ((ch ^ (row & 7)) << 3)];
            }
            #pragma unroll
            for (int mi = 0; mi < 2; ++mi)
                #pragma unroll
                for (int ni = 0; ni < 4; ++ni)
                    acc[mi][ni] = __builtin_amdgcn_mfma_f32_16x16x32_bf16(
                        afr[mi], bfr[ni], acc[mi][ni], 0, 0, 0);
        }
    }
    #pragma unroll
    for (int mi = 0; mi < 2; ++mi) {
        #pragma unroll
        for (int ni = 0; ni < 4; ++ni) {
            int n = bn + wn * 64 + ni * 16 + (lane & 15);
            float cbn = cb[n];
            #pragma unroll
            for (int r = 0; r < 4; ++r) {
                int row = wm * 32 + mi * 16 + (lane >> 4) * 4 + r;
                int m = bm + row;
                int p = m % HWN;
                xt[(size_t)m * DD + n] = f2bf(acc[mi][ni][r] + cbn + pos[(size_t)p * DD + n]);
            }
        }
    }
}

// ===== fused: [blocks 0..447] LN + k/v GEMM ; [blocks 448..479] slot init + q =====
__global__ __launch_bounds__(512) void k_kvinit(const ushort* __restrict__ xt,
        const ushort* __restrict__ kwT, const ushort* __restrict__ vwT,
        const float* __restrict__ kb, const float* __restrict__ vb,
        const float* __restrict__ lng, const float* __restrict__ lnb,
        ushort* __restrict__ kbf, ushort* __restrict__ vT,
        const float* __restrict__ noise, const float* __restrict__ mu,
        const float* __restrict__ lsig,
        const ushort* __restrict__ qwT, const float* __restrict__ qb,
        const float* __restrict__ gs, const float* __restrict__ bs,
        float* __restrict__ slots, ushort* __restrict__ qbuf){
    __shared__ ushort As[32*256];
    __shared__ float Sld[16*256];
    __shared__ float part[8][16][2];
    __shared__ float stats[16][2];
    const int t = threadIdx.x, lane = t & 63, wv = t >> 6;
    if (blockIdx.x < 448){
        const int b = blockIdx.x / 7, pblk = blockIdx.x % 7;
        {   // stage 32 rows with LayerNorm fused. 16 threads per row.
            int row = t >> 4, seg = t & 15;
            int grow = b*HWN + pblk*32 + row;
            if (grow > MTOT-1) grow = MTOT-1;
            const ushort* src = &xt[(size_t)grow*DD + seg*16];
            short8 v0 = *(const short8*)&src[0];
            short8 v1 = *(const short8*)&src[8];
            float f[16];
            #pragma unroll
            for (int j = 0; j < 8; ++j){ f[j] = bf2f((ushort)v0[j]); f[8+j] = bf2f((ushort)v1[j]); }
            float s = 0.f, sq = 0.f;
            #pragma unroll
            for (int j = 0; j < 16; ++j){ s += f[j]; sq += f[j]*f[j]; }
            #pragma unroll
            for (int m = 8; m >= 1; m >>= 1){ s += __shfl_xor(s, m, 64); sq += __shfl_xor(sq, m, 64); }
            float mean = s * (1.f/256.f);
            float rs = rsqrtf(sq*(1.f/256.f) - mean*mean + 1e-5f);
            int d0 = seg*16;
            short8 o0, o1;
            #pragma unroll
            for (int j = 0; j < 8; ++j){
                o0[j] = (short)f2bf((f[j]   - mean)*rs*lng[d0+j]   + lnb[d0+j]);
                o1[j] = (short)f2bf((f[8+j] - mean)*rs*lng[d0+8+j] + lnb[d0+8+j]);
            }
            int ch0 = seg*2;
            *(short8*)&As[row*256 + ((ch0^(row&7))<<3)] = o0;
            *(short8*)&As[row*256 + (((ch0+1)^(row&7))<<3)] = o1;
        }
        __syncthreads();
        f32x4 acck[2][2] = {}, accv[2][2] = {};
        const int n0 = wv*32;
        #pragma unroll
        for (int kt = 0; kt < 8; ++kt){
            short8 afr[2];
            #pragma unroll
            for (int mi = 0; mi < 2; ++mi){
                int row = mi*16 + (lane&15);
                int ch = kt*4 + (lane>>4);
                afr[mi] = *(const short8*)&As[row*256 + ((ch^(row&7))<<3)];
            }
            #pragma unroll
            for (int ni = 0; ni < 2; ++ni){
                int n = n0 + ni*16 + (lane&15);
                int koff = kt*32 + (lane>>4)*8;
                short8 bk = *(const short8*)&kwT[(size_t)n*DD + koff];
                short8 bv = *(const short8*)&vwT[(size_t)n*DD + koff];
                #pragma unroll
                for (int mi = 0; mi < 2; ++mi){
                    acck[mi][ni] = __builtin_amdgcn_mfma_f32_16x16x32_bf16(afr[mi], bk, acck[mi][ni],0,0,0);
                    accv[mi][ni] = __builtin_amdgcn_mfma_f32_16x16x32_bf16(afr[mi], bv, accv[mi][ni],0,0,0);
                }
            }
        }
        #pragma unroll
        for (int mi = 0; mi < 2; ++mi){
            #pragma unroll
            for (int ni = 0; ni < 2; ++ni){
                int n = n0 + ni*16 + (lane&15);
                float kbn = kb[n], vbn = vb[n];
                int pl0 = pblk*32 + mi*16 + (lane>>4)*4;
                us4 pk;
                #pragma unroll
                for (int r = 0; r < 4; ++r){
                    kbf[((size_t)b*KVPAD + pl0 + r)*DD + n] = f2bf(acck[mi][ni][r] + kbn);
                    pk[r] = f2bf(accv[mi][ni][r] + vbn);
                }
                *(us4*)&vT[((size_t)b*DD + n)*KVPAD + pl0] = pk;
            }
        }
    } else {
        // ===== slot init: slots0 + LN_s + q (reuses As as Ysn) =====
        ushort* Ysn = As;
        const int bb = blockIdx.x - 448, rbase = bb*16;
        const int w = wv;
        {
            int row = t>>5, ch = t&31; int d = ch*8;
            f32x4 n0 = *(const f32x4*)&noise[(size_t)(rbase+row)*DD + d];
            f32x4 n1 = *(const f32x4*)&noise[(size_t)(rbase+row)*DD + d + 4];
            f32x4 m0 = *(const f32x4*)&mu[d];
            f32x4 m1 = *(const f32x4*)&mu[d+4];
            f32x4 l0 = *(const f32x4*)&lsig[d];
            f32x4 l1 = *(const f32x4*)&lsig[d+4];
            f32x4 s0, s1;
            #pragma unroll
            for (int j = 0; j < 4; ++j){
                s0[j] = m0[j] + expf(l0[j])*n0[j];
                s1[j] = m1[j] + expf(l1[j])*n1[j];
            }
            *(f32x4*)&slots[(size_t)(rbase+row)*DD + d] = s0;
            *(f32x4*)&slots[(size_t)(rbase+row)*DD + d + 4] = s1;
            *(f32x4*)&Sld[row*256 + d] = s0;
            *(f32x4*)&Sld[row*256 + d + 4] = s1;
        }
        __syncthreads();
        f32x4 sv[2];
        #pragma unroll
        for (int sub = 0; sub < 2; ++sub){
            int d0 = w*32 + sub*16 + (lane>>4)*4;
            sv[sub] = *(const f32x4*)&Sld[(lane&15)*256 + d0];
        }
        {
            float lsum = 0.f, lsq = 0.f;
            #pragma unroll
            for (int sub = 0; sub < 2; ++sub)
                #pragma unroll
                for (int r = 0; r < 4; ++r){ float v = sv[sub][r]; lsum += v; lsq += v*v; }
            lsum += __shfl_xor(lsum, 16, 64); lsum += __shfl_xor(lsum, 32, 64);
            lsq  += __shfl_xor(lsq, 16, 64);  lsq  += __shfl_xor(lsq, 32, 64);
            if (lane < 16){ part[w][lane][0] = lsum; part[w][lane][1] = lsq; }
        }
        __syncthreads();
        if (t < 16){
            float a = 0.f, c = 0.f;
            #pragma unroll
            for (int i = 0; i < 8; ++i){ a += part[i][t][0]; c += part[i][t][1]; }
            float mean = a*(1.f/256.f);
            stats[t][0] = mean;
            stats[t][1] = rsqrtf(c*(1.f/256.f) - mean*mean + 1e-5f);
        }
        __syncthreads();
        {
            int slot = lane&15;
            float mean = stats[slot][0], rs = stats[slot][1];
            #pragma unroll
            for (int sub = 0; sub < 2; ++sub){
                int d0 = w*32 + sub*16 + (lane>>4)*4;
                f32x4 g4 = *(const f32x4*)&gs[d0];
                f32x4 b4 = *(const f32x4*)&bs[d0];
                us4 o;
                #pragma unroll
                for (int r = 0; r < 4; ++r) o[r] = f2bf((sv[sub][r]-mean)*rs*g4[r] + b4[r]);
                int ch = d0>>3;
                *(us4*)&Ysn[slot*256 + ((ch^(slot&7))<<3) + (d0&7)] = o;
            }
        }
        __syncthreads();
        f32x4 qa[2] = {};
        #pragma unroll
        for (int kt = 0; kt < 8; ++kt){
            short8 ysn = ldsY(Ysn, 256, kt, lane);
            #pragma unroll
            for (int sub = 0; sub < 2; ++sub){
                int nrow = w*32 + sub*16 + (lane&15);
                short8 xx = gX(qwT, 256, nrow, kt, lane);
                qa[sub] = __builtin_amdgcn_mfma_f32_16x16x32_bf16(xx, ysn, qa[sub], 0,0,0);
            }
        }
        #pragma unroll
        for (int sub = 0; sub < 2; ++sub){
            int qd0 = w*32 + sub*16 + (lane>>4)*4;
            f32x4 qb4 = *(const f32x4*)&qb[qd0];
            us4 o;
            #pragma unroll
            for (int r = 0; r < 4; ++r) o[r] = f2bf((qa[sub][r]+qb4[r])*0.0625f);
            *(us4*)&qbuf[(size_t)(rbase+(lane&15))*DD + qd0] = o;
        }
    }
}

// softmax-over-slots epilogue for one 16-key tile; returns partial key-sum
__device__ __forceinline__ float sm_ep(f32x4 acc, int f, int lane, ushort* Xat, int srow){
    int k0 = f*16 + (lane>>4)*4;
    us4 o;
    float ps = 0.f;
    #pragma unroll
    for (int r = 0; r < 4; ++r){
        float v = acc[r];
        float mx = v;
        mx = fmaxf(mx, __shfl_xor(mx, 1, 64));
        mx = fmaxf(mx, __shfl_xor(mx, 2, 64));
        mx = fmaxf(mx, __shfl_xor(mx, 4, 64));
        float e = expf(v - mx);
        float se = e;
        se += __shfl_xor(se, 1, 64);
        se += __shfl_xor(se, 2, 64);
        se += __shfl_xor(se, 4, 64);
        float val = e/se + 1e-8f;
        if (k0 + r >= HWN) val = 0.f;
        ps += val;
        o[r] = f2bf(val);
    }
    int ch = k0 >> 3;
    *(us4*)&Xat[srow*256 + ((ch^(srow&7))<<3) + (k0&7)] = o;
    return ps;
}

// ======================= merged slot iteration, 16 waves =======================
__global__ __launch_bounds__(1024, 2) void k_slot(
        const ushort* __restrict__ qbuf, const ushort* __restrict__ kbf,
        const ushort* __restrict__ vT, float* __restrict__ slots,
        ushort* __restrict__ qout,
        const ushort* __restrict__ wihT, const ushort* __restrict__ whhT,
        const float* __restrict__ bih, const float* __restrict__ bhh,
        const ushort* __restrict__ w1T, const float* __restrict__ b1,
        const ushort* __restrict__ w2T, const float* __restrict__ b2,
        const float* __restrict__ gff, const float* __restrict__ bff,
        const float* __restrict__ gs, const float* __restrict__ bs,
        const ushort* __restrict__ qwT, const float* __restrict__ qb,
        float* __restrict__ out_slots, float* __restrict__ out_attn,
        int final_){
    __shared__ ushort Yq[16*256];
    __shared__ ushort Xat[16*256];
    __shared__ ushort Yupd[16*256];
    __shared__ ushort Yslb[16*256];
    __shared__ ushort Ysn[16*256];
    __shared__ ushort Yh[16*512];
    __shared__ float wpart[16][16];
    __shared__ float part[16][16][2];
    const int t = threadIdx.x, lane = t & 63, w = t >> 6;
    const int b = blockIdx.x;
    const int rbase = b * NSLOT;
    const int srow = lane & 15;
    const int srd = (srow < NSLOT) ? srow : 0;

    if (t < 256){
        int row = t>>5, ch = t&31;
        short8 v = *(const short8*)&qbuf[(size_t)(rbase+row)*DD + ch*8];
        *(short8*)&Yq[row*256 + ((ch^(row&7))<<3)] = v;
        f32x4 s0 = *(const f32x4*)&slots[(size_t)(rbase+row)*DD + ch*8];
        f32x4 s1 = *(const f32x4*)&slots[(size_t)(rbase+row)*DD + ch*8 + 4];
        short8 sv;
        #pragma unroll
        for (int j = 0; j < 4; ++j){ sv[j] = (short)f2bf(s0[j]); sv[4+j] = (short)f2bf(s1[j]); }
        *(short8*)&Yslb[row*256 + ((ch^(row&7))<<3)] = sv;
    } else if (t < 512){
        int i = t - 256;
        int row = (i>>5) + 8, ch = i&31;
        short8 z;
        #pragma unroll
        for (int j = 0; j < 8; ++j) z[j] = 0;
        *(short8*)&Yq[row*256 + ((ch^(row&7))<<3)] = z;
        *(short8*)&Yupd[row*256 + ((ch^(row&7))<<3)] = z;
        *(short8*)&Yslb[row*256 + ((ch^(row&7))<<3)] = z;
    }
    __syncthreads();
    // ===== QK^T + softmax over slots: 1 key-tile per wave (14 of 16 active) =====
    if (w < 14){
        short8 yf[8];
        #pragma unroll
        for (int kt = 0; kt < 8; ++kt) yf[kt] = ldsY(Yq, 256, kt, lane);
        const ushort* kb_ = kbf + (size_t)b*KVPAD*DD;
        const int r0 = w*16 + (lane&15);
        short8 xa[2];
        xa[0] = gX(kb_, 256, r0, 0, lane);
        f32x4 accA = {};
        #pragma unroll
        for (int kt = 0; kt < 8; ++kt){
            int cu = kt & 1, nx = cu ^ 1;
            if (kt < 7) xa[nx] = gX(kb_, 256, r0, kt+1, lane);
            accA = __builtin_amdgcn_mfma_f32_16x16x32_bf16(xa[cu], yf[kt], accA, 0,0,0);
        }
        float ps = sm_ep(accA, w, lane, Xat, srow);
        ps += __shfl_xor(ps, 16, 64);
        ps += __shfl_xor(ps, 32, 64);
        if (lane < 16) wpart[w][lane] = ps;
    } else {
        if (lane < 16) wpart[w][lane] = 0.f;
    }
    __syncthreads();
    // ===== PV: 1 d-tile per wave; per-thread invk from wpart (no extra barrier) =====
    f32x4 pv;
    {
        short8 xat[7];
        #pragma unroll
        for (int kt = 0; kt < 7; ++kt) xat[kt] = ldsY(Xat, 256, kt, lane);
        const ushort* vb_ = vT + (size_t)b*DD*KVPAD;
        const int d0r = w*16 + (lane&15);
        short8 ya[2];
        ya[0] = gX(vb_, KVPAD, d0r, 0, lane);
        f32x4 aA = {};
        #pragma unroll
        for (int kt = 0; kt < 7; ++kt){
            int cu = kt & 1, nx = cu ^ 1;
            if (kt < 6) ya[nx] = gX(vb_, KVPAD, d0r, kt+1, lane);
            aA = __builtin_amdgcn_mfma_f32_16x16x32_bf16(xat[kt], ya[cu], aA, 0,0,0);
        }
        pv = aA;
    }
    {
        f32x4 iv;
        #pragma unroll
        for (int r = 0; r < 4; ++r){
            int s2 = (lane>>4)*4 + r;
            float s = 0.f;
            #pragma unroll
            for (int i = 0; i < 16; ++i) s += wpart[i][s2];
            iv[r] = 1.f/s;
        }
        int d0 = w*16;
        #pragma unroll
        for (int r = 0; r < 4; ++r){
            int s2 = (lane>>4)*4 + r;
            if (s2 < NSLOT){
                int d = d0 + (lane&15);
                int ch = d >> 3;
                Yupd[s2*256 + ((ch^(s2&7))<<3) + (d&7)] = f2bf(pv[r]*iv[r]);
            }
        }
    }
    if (final_){
        for (int idx = t; idx < NSLOT*HWN; idx += 1024){
            int slot = idx/HWN, key = idx - slot*HWN;
            float s = 0.f;
            #pragma unroll
            for (int i = 0; i < 16; ++i) s += wpart[i][slot];
            int ch = key >> 3;
            out_attn[(size_t)b*NSLOT*HWN + idx] =
                bf2f(Xat[slot*256 + ((ch^(slot&7))<<3) + (key&7)]) / s;
        }
    }
    __syncthreads();
    // ===== gi/gh GEMMs: 3 gate-frags per wave =====
    f32x4 gi[3] = {}, gh[3] = {};
    {
        int nrw[3];
        #pragma unroll
        for (int g = 0; g < 3; ++g) nrw[g] = g*256 + w*16 + (lane&15);
        short8 xw[2][6];
        #pragma unroll
        for (int g = 0; g < 3; ++g){
            xw[0][g]   = gX(wihT, 256, nrw[g], 0, lane);
            xw[0][3+g] = gX(whhT, 256, nrw[g], 0, lane);
        }
        #pragma unroll
        for (int kt = 0; kt < 8; ++kt){
            int cu = kt & 1, nx = cu ^ 1;
            if (kt < 7){
                #pragma unroll
                for (int g = 0; g < 3; ++g){
                    xw[nx][g]   = gX(wihT, 256, nrw[g], kt+1, lane);
                    xw[nx][3+g] = gX(whhT, 256, nrw[g], kt+1, lane);
                }
            }
            short8 yu = ldsY(Yupd, 256, kt, lane);
            short8 ys = ldsY(Yslb, 256, kt, lane);
            #pragma unroll
            for (int g = 0; g < 3; ++g){
                gi[g] = __builtin_amdgcn_mfma_f32_16x16x32_bf16(xw[cu][g],   yu, gi[g], 0,0,0);
                gh[g] = __builtin_amdgcn_mfma_f32_16x16x32_bf16(xw[cu][3+g], ys, gh[g], 0,0,0);
            }
        }
    }
    // ===== GRU combine (lane-local triplets, 16 dims per wave) =====
    f32x4 snew;
    {
        int d0 = w*16 + (lane>>4)*4;
        f32x4 sp  = *(const f32x4*)&slots[(size_t)(rbase + srd)*DD + d0];
        f32x4 bir = *(const f32x4*)&bih[d0];
        f32x4 biz = *(const f32x4*)&bih[256 + d0];
        f32x4 bin = *(const f32x4*)&bih[512 + d0];
        f32x4 bhr = *(const f32x4*)&bhh[d0];
        f32x4 bhz = *(const f32x4*)&bhh[256 + d0];
        f32x4 bhn = *(const f32x4*)&bhh[512 + d0];
        #pragma unroll
        for (int r = 0; r < 4; ++r){
            float ir = gi[0][r] + bir[r];
            float iz = gi[1][r] + biz[r];
            float in_ = gi[2][r] + bin[r];
            float hr = gh[0][r] + bhr[r];
            float hz = gh[1][r] + bhz[r];
            float hn = gh[2][r] + bhn[r];
            float rr = sigm(ir + hr);
            float zz = sigm(iz + hz);
            float nn = tanhf(in_ + rr*hn);
            snew[r] = (1.f - zz)*nn + zz*sp[r];
        }
    }
    // ===== LN_ff (single-barrier) =====
    {
        float lsum = 0.f, lsq = 0.f;
        #pragma unroll
        for (int r = 0; r < 4; ++r){ float v = snew[r]; lsum += v; lsq += v*v; }
        lsum += __shfl_xor(lsum, 16, 64); lsum += __shfl_xor(lsum, 32, 64);
        lsq  += __shfl_xor(lsq, 16, 64);  lsq  += __shfl_xor(lsq, 32, 64);
        if (lane < 16){ part[w][lane][0] = lsum; part[w][lane][1] = lsq; }
    }
    __syncthreads();
    {
        float a = 0.f, c = 0.f;
        #pragma unroll
        for (int i = 0; i < 16; ++i){ a += part[i][srow][0]; c += part[i][srow][1]; }
        float mean = a*(1.f/256.f);
        float rs = rsqrtf(c*(1.f/256.f) - mean*mean + 1e-5f);
        int d0 = w*16 + (lane>>4)*4;
        f32x4 g4 = *(const f32x4*)&gff[d0];
        f32x4 b4 = *(const f32x4*)&bff[d0];
        us4 o;
        #pragma unroll
        for (int r = 0; r < 4; ++r) o[r] = f2bf((snew[r]-mean)*rs*g4[r] + b4[r]);
        int ch = d0 >> 3;
        *(us4*)&Ysn[srow*256 + ((ch^(srow&7))<<3) + (d0&7)] = o;
    }
    __syncthreads();
    // ===== ff1: 2 frags per wave =====
    {
        int nr1[2];
        #pragma unroll
        for (int s2 = 0; s2 < 2; ++s2) nr1[s2] = w*32 + s2*16 + (lane&15);
        short8 xw1[2][2];
        #pragma unroll
        for (int s2 = 0; s2 < 2; ++s2) xw1[0][s2] = gX(w1T, 256, nr1[s2], 0, lane);
        f32x4 hh[2] = {};
        #pragma unroll
        for (int kt = 0; kt < 8; ++kt){
            int cu = kt & 1, nx = cu ^ 1;
            if (kt < 7){
                #pragma unroll
                for (int s2 = 0; s2 < 2; ++s2) xw1[nx][s2] = gX(w1T, 256, nr1[s2], kt+1, lane);
            }
            short8 ysn = ldsY(Ysn, 256, kt, lane);
            #pragma unroll
            for (int s2 = 0; s2 < 2; ++s2)
                hh[s2] = __builtin_amdgcn_mfma_f32_16x16x32_bf16(xw1[cu][s2], ysn, hh[s2], 0,0,0);
        }
        #pragma unroll
        for (int s2 = 0; s2 < 2; ++s2){
            int n0 = w*32 + s2*16 + (lane>>4)*4;
            f32x4 b14 = *(const f32x4*)&b1[n0];
            us4 o;
            #pragma unroll
            for (int r = 0; r < 4; ++r) o[r] = f2bf(fmaxf(hh[s2][r] + b14[r], 0.f));
            int ch = n0 >> 3;
            *(us4*)&Yh[srow*512 + ((ch^(srow&7))<<3) + (n0&7)] = o;
        }
    }
    __syncthreads();
    // ===== ff2 + residual: 1 frag per wave, K=512 =====
    f32x4 ns;
    {
        int nr2 = w*16 + (lane&15);
        short8 xw2[2];
        xw2[0] = gX(w2T, 512, nr2, 0, lane);
        f32x4 o2 = {};
        #pragma unroll
        for (int kt = 0; kt < 16; ++kt){
            int cu = kt & 1, nx = cu ^ 1;
            if (kt < 15) xw2[nx] = gX(w2T, 512, nr2, kt+1, lane);
            short8 yh = ldsY(Yh, 512, kt, lane);
            o2 = __builtin_amdgcn_mfma_f32_16x16x32_bf16(xw2[cu], yh, o2, 0,0,0);
        }
        float* dst = final_ ? out_slots : slots;
        int d0 = w*16 + (lane>>4)*4;
        f32x4 b24 = *(const f32x4*)&b2[d0];
        #pragma unroll
        for (int r = 0; r < 4; ++r) ns[r] = o2[r] + b24[r] + snew[r];
        if (srow < NSLOT)
            *(f32x4*)&dst[(size_t)(rbase + srow)*DD + d0] = ns;
    }
    if (final_) return;
    // ===== LN_s + next q (single-barrier LN) =====
    {
        float lsum = 0.f, lsq = 0.f;
        #pragma unroll
        for (int r = 0; r < 4; ++r){ float v = ns[r]; lsum += v; lsq += v*v; }
        lsum += __shfl_xor(lsum, 16, 64); lsum += __shfl_xor(lsum, 32, 64);
        lsq  += __shfl_xor(lsq, 16, 64);  lsq  += __shfl_xor(lsq, 32, 64);
        if (lane < 16){ part[w][lane][0] = lsum; part[w][lane][1] = lsq; }
    }
    __syncthreads();
    {
        float a = 0.f, c = 0.f;
        #pragma unroll
        for (int i = 0; i < 16; ++i){ a += part[i][srow][0]; c += part[i][srow][1]; }
        float mean = a*(1.f/256.f);
        float rs = rsqrtf(c*(1.f/256.f) - mean*mean + 1e-5f);
        int d0 = w*16 + (lane>>4)*4;
        f32x4 g4 = *(const f32x4*)&gs[d0];
        f32x4 b4 = *(const f32x4*)&bs[d0];
        us4 o;
        #pragma unroll
        for (int r = 0; r < 4; ++r) o[r] = f2bf((ns[r]-mean)*rs*g4[r] + b4[r]);
        int ch = d0 >> 3;
        *(us4*)&Ysn[srow*256 + ((ch^(srow&7))<<3) + (d0&7)] = o;
    }
    __syncthreads();
    {
        int nrq = w*16 + (lane&15);
        short8 xq[2];
        xq[0] = gX(qwT, 256, nrq, 0, lane);
        f32x4 qa = {};
        #pragma unroll
        for (int kt = 0; kt < 8; ++kt){
            int cu = kt & 1, nx = cu ^ 1;
            if (kt < 7) xq[nx] = gX(qwT, 256, nrq, kt+1, lane);
            short8 ysn = ldsY(Ysn, 256, kt, lane);
            qa = __builtin_amdgcn_mfma_f32_16x16x32_bf16(xq[cu], ysn, qa, 0,0,0);
        }
        int qd0 = w*16 + (lane>>4)*4;
        f32x4 qb4 = *(const f32x4*)&qb[qd0];
        us4 o;
        #pragma unroll
        for (int r = 0; r < 4; ++r) o[r] = f2bf((qa[r]+qb4[r])*0.0625f);
        if (srow < NSLOT)
            *(us4*)&qout[(size_t)(rbase + srow)*DD + qd0] = o;
    }
}

extern "C" void kernel_launch(void* const* d_in, const int* in_sizes, int n_in,
                              void* d_out, int out_size, void* d_ws, size_t ws_size,
                              hipStream_t stream) {
    const float* x      = (const float*)d_in[0];
    const float* noise  = (const float*)d_in[1];
    const float* conv_w = (const float*)d_in[2];
    const float* conv_b = (const float*)d_in[3];
    const float* pos    = (const float*)d_in[4];
    const float* mu     = (const float*)d_in[5];
    const float* logsig = (const float*)d_in[6];
    const float* qw  = (const float*)d_in[7];
    const float* qb  = (const float*)d_in[8];
    const float* kw  = (const float*)d_in[9];
    const float* kb  = (const float*)d_in[10];
    const float* vw  = (const float*)d_in[11];
    const float* vb  = (const float*)d_in[12];
    const float* wih = (const float*)d_in[13];
    const float* whh = (const float*)d_in[14];
    const float* bih = (const float*)d_in[15];
    const float* bhh = (const float*)d_in[16];
    const float* w1  = (const float*)d_in[17];
    const float* b1  = (const float*)d_in[18];
    const float* w2  = (const float*)d_in[19];
    const float* b2  = (const float*)d_in[20];
    const float* g_in = (const float*)d_in[21];
    const float* b_in = (const float*)d_in[22];
    const float* g_s  = (const float*)d_in[23];
    const float* b_s  = (const float*)d_in[24];
    const float* g_ff = (const float*)d_in[25];
    const float* b_ff = (const float*)d_in[26];

    char* w = (char*)d_ws;
    ushort* kbf    = (ushort*)w; w += (size_t)BB*KVPAD*DD*2;
    ushort* vT     = (ushort*)w; w += (size_t)BB*DD*KVPAD*2;
    ushort* cwT    = (ushort*)w; w += (size_t)DD*CIN*2;
    ushort* qwT    = (ushort*)w; w += (size_t)DD*DD*2;
    ushort* kwT    = (ushort*)w; w += (size_t)DD*DD*2;
    ushort* vwT    = (ushort*)w; w += (size_t)DD*DD*2;
    ushort* wihT   = (ushort*)w; w += (size_t)768*DD*2;
    ushort* whhT   = (ushort*)w; w += (size_t)768*DD*2;
    ushort* w1T    = (ushort*)w; w += (size_t)512*DD*2;
    ushort* w2T    = (ushort*)w; w += (size_t)DD*512*2;
    ushort* qbb    = (ushort*)w; w += (size_t)BB*NSLOT*DD*2;
    float*  slotsb = (float*)w;  w += (size_t)BB*NSLOT*DD*4;
    ushort* xt     = (ushort*)w; w += (size_t)MTOT*DD*2;

    float* out_slots = (float*)d_out;
    float* out_attn  = (float*)d_out + (size_t)BB*NSLOT*DD;

    TD8 td;
    td.a[0] = { conv_w, cwT, 2048, 256,    0 };
    td.a[1] = { qw,     qwT,  256, 256,  512 };
    td.a[2] = { kw,     kwT,  256, 256,  576 };
    td.a[3] = { vw,     vwT,  256, 256,  640 };
    td.a[4] = { wih,    wihT, 256, 768,  704 };
    td.a[5] = { whh,    whhT, 256, 768,  896 };
    td.a[6] = { w1,     w1T,  256, 512, 1088 };
    td.a[7] = { w2,     w2T,  512, 256, 1216 };

    k_prep<<<1344, 256, 0, stream>>>(td);
    k_proj<<<392, 256, 0, stream>>>(x, cwT, conv_b, pos, xt);
    k_kvinit<<<480, 512, 0, stream>>>(xt, kwT, vwT, kb, vb, g_in, b_in, kbf, vT,
                                      noise, mu, logsig, qwT, qb, g_s, b_s,
                                      slotsb, qbb);
    for (int it = 0; it < 3; ++it){
        k_slot<<<BB, 1024, 0, stream>>>(qbb, kbf, vT, slotsb, qbb,
                                        wihT, whhT, bih, bhh, w1T, b1, w2T, b2,
                                        g_ff, b_ff, g_s, b_s, qwT, qb,
                                        out_slots, out_attn, it == 2);
    }
}